// Round 6
// baseline (281.601 us; speedup 1.0000x reference)
//
#include <hip/hip_runtime.h>
#include <stdint.h>

typedef _Float16 h8 __attribute__((ext_vector_type(8)));
typedef _Float16 h4 __attribute__((ext_vector_type(4)));
typedef float f32x4 __attribute__((ext_vector_type(4)));
typedef uint32_t u32x4 __attribute__((ext_vector_type(4)));

#if __has_builtin(__builtin_amdgcn_exp2f)
#define EXP2(x) __builtin_amdgcn_exp2f(x)
#else
#define EXP2(x) exp2f(x)
#endif

// workspace map (<= 51380224 bytes)
#define WS_PWH  0u          // _Float16 [128][1024]  (dead after gemm1; mlm overwrites)
#define WS_WH   262144u     // _Float16 [384][128]   (dead after gemm2; mll overwrites)
#define WS_BC   600064u     // float [384]
#define WS_FT   1048576u    // _Float16 [4][4096][1024] feats^T; F2D aliases first 256B of rows
#define WS_QKVT 34603008u   // _Float16 [4][4096][384] q|k|v, n-major (v slice unused)
#define WS_VT   47185920u   // _Float16 [4][128][4096] v, d-major
#define WS_OP   WS_FT       // _Float16 [32 pb][128 d][4096 n] normalized partial O
#define WS_MLM  0u          // float [32][4096] running max (log2 domain)
#define WS_MLL  524288u     // float [32][4096] running sum

__device__ __forceinline__ void gll16(const void* g, void* l) {
  __builtin_amdgcn_global_load_lds((const __attribute__((address_space(1))) unsigned int*)g,
                                   (__attribute__((address_space(3))) unsigned int*)l, 16, 0, 0);
}

// ---------------- kernel 0: casts + combined bias bc = b + W*pb; q-weights scaled by log2(e) ----------------
__global__ void k_cvt(const float* __restrict__ pw, const float* __restrict__ pb,
                      const float* __restrict__ w1, const float* __restrict__ b1,
                      const float* __restrict__ w2, const float* __restrict__ b2,
                      const float* __restrict__ w3, const float* __restrict__ b3,
                      _Float16* __restrict__ PWh, _Float16* __restrict__ Wh,
                      float* __restrict__ bc)
{
  const float LOG2E = 1.4426950408889634f;
  int idx = blockIdx.x * 256 + threadIdx.x;
  if (idx < 131072) {
    PWh[idx] = (_Float16)pw[idx];
  } else {
    int j = idx - 131072;
    if (j < 49152) {
      int g = j >> 14, rem = j & 16383;
      const float* wg = (g == 0) ? w1 : (g == 1 ? w2 : w3);
      float v = wg[rem];
      if (g == 0) v *= LOG2E;                        // q in log2 domain
      Wh[j] = (_Float16)v;
    }
  }
  if (idx < 384) {
    int g = idx >> 7, o = idx & 127;
    const float* wg = (g == 0) ? w1 : (g == 1 ? w2 : w3);
    const float* bg = (g == 0) ? b1 : (g == 1 ? b2 : b3);
    float s = bg[o];
    for (int c = 0; c < 128; ++c) s += wg[o * 128 + c] * pb[c];
    if (g == 0) s *= LOG2E;
    bc[idx] = s;
  }
}

// ---------------- kernel 1: feats (b,1024,4096) f32 -> feats^T (b,4096,1024) fp16 ----------------
__global__ void k_featT(const float* __restrict__ feats, _Float16* __restrict__ FT)
{
  __shared__ float tile[64][65];
  const int ck0 = blockIdx.x * 64, n0 = blockIdx.y * 64, b = blockIdx.z;
  const int t = threadIdx.x;
  const float* src = feats + ((size_t)(b * 1024 + ck0)) * 4096 + n0;
  #pragma unroll
  for (int p = 0; p < 4; ++p) {
    int i = t + p * 256, row = i >> 4, slot = i & 15;
    float4 g = *(const float4*)(src + (size_t)row * 4096 + slot * 4);
    tile[row][slot * 4 + 0] = g.x; tile[row][slot * 4 + 1] = g.y;
    tile[row][slot * 4 + 2] = g.z; tile[row][slot * 4 + 3] = g.w;
  }
  __syncthreads();
  _Float16* dst = FT + ((size_t)(b * 4096 + n0)) * 1024 + ck0;
  #pragma unroll
  for (int p = 0; p < 4; ++p) {
    int i = t + p * 256, n = i >> 4, cs = i & 15;
    h4 o;
    #pragma unroll
    for (int j = 0; j < 4; ++j) o[j] = (_Float16)tile[cs * 4 + j][n];
    *(h4*)(dst + (size_t)n * 1024 + cs * 4) = o;
  }
}

// ---------------- kernel 2: GEMM1  F2D[b][n][128] = FT[b][n][:] . PWh[o][:] ----------------
__global__ __launch_bounds__(256) void k_gemm1(char* __restrict__ ftbase,
                                               const _Float16* __restrict__ PWh)
{
  extern __shared__ char smem[];                     // 2 bufs x (A 8K + B 16K) = 48K
  const int t = threadIdx.x, lane = t & 63, w = t >> 6;
  const int lo = lane & 15, hi = lane >> 4;
  const int n0 = blockIdx.x * 64, b = blockIdx.y;
  const int wr = w >> 1, wc = w & 1;
  const int nb = wr * 32, ob = wc * 64;

  uint4 areg[2], wreg[4];
  const char* Fbase = ftbase + ((size_t)(b * 4096 + n0)) * 2048;
  const char* Wbase = (const char*)PWh;

  auto stageload = [&](int s) {
    #pragma unroll
    for (int p = 0; p < 2; ++p) {
      int i = t + p * 256, row = i >> 3, slot = i & 7;
      areg[p] = *(const uint4*)(Fbase + (size_t)row * 2048 + s * 128 + slot * 16);
    }
    #pragma unroll
    for (int p = 0; p < 4; ++p) {
      int i = t + p * 256, row = i >> 3, slot = i & 7;
      wreg[p] = *(const uint4*)(Wbase + (size_t)row * 2048 + s * 128 + slot * 16);
    }
  };
  auto stagewrite = [&](int buf) {
    char* base = smem + buf * 24576;
    #pragma unroll
    for (int p = 0; p < 2; ++p) {
      int i = t + p * 256, row = i >> 3, slot = i & 7;
      *(uint4*)(base + row * 128 + ((slot * 16) ^ ((row & 7) << 4))) = areg[p];
    }
    #pragma unroll
    for (int p = 0; p < 4; ++p) {
      int i = t + p * 256, row = i >> 3, slot = i & 7;
      *(uint4*)(base + 8192 + row * 128 + ((slot * 16) ^ ((row & 7) << 4))) = wreg[p];
    }
  };

  const f32x4 zero4 = {0.f, 0.f, 0.f, 0.f};
  f32x4 acc[2][4];
  #pragma unroll
  for (int i2 = 0; i2 < 2; ++i2)
    #pragma unroll
    for (int j2 = 0; j2 < 4; ++j2) acc[i2][j2] = zero4;

  stageload(0); stagewrite(0);
  for (int s = 0; s < 16; ++s) {
    __syncthreads();
    if (s < 15) stageload(s + 1);
    const char* base = smem + (s & 1) * 24576;
    #pragma unroll
    for (int kk = 0; kk < 2; ++kk) {
      const int cb = kk * 64 + hi * 16;
      h8 af[2], bf[4];
      #pragma unroll
      for (int i2 = 0; i2 < 2; ++i2) {
        int row = nb + i2 * 16 + lo;
        af[i2] = *(const h8*)(base + row * 128 + (cb ^ ((row & 7) << 4)));
      }
      #pragma unroll
      for (int j2 = 0; j2 < 4; ++j2) {
        int row = ob + j2 * 16 + lo;
        bf[j2] = *(const h8*)(base + 8192 + row * 128 + (cb ^ ((row & 7) << 4)));
      }
      #pragma unroll
      for (int i2 = 0; i2 < 2; ++i2)
        #pragma unroll
        for (int j2 = 0; j2 < 4; ++j2)
          acc[i2][j2] = __builtin_amdgcn_mfma_f32_16x16x32_f16(af[i2], bf[j2], acc[i2][j2], 0, 0, 0);
    }
    if (s < 15) stagewrite((s + 1) & 1);
  }

  #pragma unroll
  for (int i2 = 0; i2 < 2; ++i2)
    #pragma unroll
    for (int j2 = 0; j2 < 4; ++j2)
      #pragma unroll
      for (int r = 0; r < 4; ++r) {
        int n = n0 + nb + i2 * 16 + hi * 4 + r;
        int o = ob + j2 * 16 + lo;
        *(_Float16*)(ftbase + ((size_t)(b * 4096 + n)) * 2048 + o * 2) = (_Float16)acc[i2][j2][r];
      }
}

// ---------------- kernel 3: GEMM2  qkvt = F2D . Wh + bc; v-group (bx==2) goes to vt via LDS bounce ----------------
__global__ void k_gemm2(const char* __restrict__ ftbase, const _Float16* __restrict__ Wh,
                        const float* __restrict__ bc, _Float16* __restrict__ qkvt,
                        _Float16* __restrict__ vt)
{
  extern __shared__ char smem[];                     // A 32K + B 32K; bx==2 reuses for vtile
  const int t = threadIdx.x, lane = t & 63, w = t >> 6;
  const int lo = lane & 15, hi = lane >> 4;
  const int bx = blockIdx.x, n0 = blockIdx.y * 128, b = blockIdx.z;
  const int wr = w >> 1, wc = w & 1;
  const int nb = wr * 64, ob = wc * 64;

  #pragma unroll
  for (int q = 0; q < 8; ++q) {
    int c = w * 8 + q;
    int row = c * 4 + (lane >> 4);
    int col = ((lane & 15) * 16) ^ ((row & 7) << 4);
    gll16(ftbase + ((size_t)(b * 4096 + n0 + row)) * 2048 + col, smem + c * 1024);
    gll16((const char*)Wh + (size_t)(bx * 128 + row) * 256 + col, smem + 32768 + c * 1024);
  }
  __syncthreads();

  const f32x4 zero4 = {0.f, 0.f, 0.f, 0.f};
  f32x4 acc[4][4];
  #pragma unroll
  for (int i2 = 0; i2 < 4; ++i2)
    #pragma unroll
    for (int j2 = 0; j2 < 4; ++j2) acc[i2][j2] = zero4;

  #pragma unroll
  for (int kk = 0; kk < 4; ++kk) {
    const int cb = kk * 64 + hi * 16;
    h8 af[4], bf[4];
    #pragma unroll
    for (int i2 = 0; i2 < 4; ++i2) {
      int row = nb + i2 * 16 + lo;
      af[i2] = *(const h8*)(smem + row * 256 + (cb ^ ((row & 7) << 4)));
    }
    #pragma unroll
    for (int j2 = 0; j2 < 4; ++j2) {
      int row = ob + j2 * 16 + lo;
      bf[j2] = *(const h8*)(smem + 32768 + row * 256 + (cb ^ ((row & 7) << 4)));
    }
    #pragma unroll
    for (int i2 = 0; i2 < 4; ++i2)
      #pragma unroll
      for (int j2 = 0; j2 < 4; ++j2)
        acc[i2][j2] = __builtin_amdgcn_mfma_f32_16x16x32_f16(af[i2], bf[j2], acc[i2][j2], 0, 0, 0);
  }

  if (bx < 2) {
    #pragma unroll
    for (int j2 = 0; j2 < 4; ++j2) {
      int o = bx * 128 + ob + j2 * 16 + lo;
      float bias = bc[o];
      #pragma unroll
      for (int i2 = 0; i2 < 4; ++i2)
        #pragma unroll
        for (int r = 0; r < 4; ++r) {
          int n = n0 + nb + i2 * 16 + hi * 4 + r;
          qkvt[((size_t)(b * 4096 + n)) * 384 + o] = (_Float16)(acc[i2][j2][r] + bias);
        }
    }
  } else {
    // v-group: bounce through LDS (padded stride 272B) and store transposed to vt[b][d][m]
    __syncthreads();                                 // A/B reads done; reuse smem
    #pragma unroll
    for (int j2 = 0; j2 < 4; ++j2) {
      int o = ob + j2 * 16 + lo;                     // d = o (local 0..127)
      float bias = bc[256 + o];
      #pragma unroll
      for (int i2 = 0; i2 < 4; ++i2) {
        int nl = nb + i2 * 16 + hi * 4;
        h4 v4;
        #pragma unroll
        for (int r = 0; r < 4; ++r) v4[r] = (_Float16)(acc[i2][j2][r] + bias);
        *(h4*)(smem + o * 272 + nl * 2) = v4;
      }
    }
    __syncthreads();
    #pragma unroll
    for (int p2 = 0; p2 < 8; ++p2) {
      int i = t + p2 * 256, d = i >> 4, ch = i & 15;
      uint4 v = *(const uint4*)(smem + d * 272 + ch * 16);
      *(uint4*)((char*)vt + ((size_t)(b * 128 + d)) * 8192 + (n0 + ch * 8) * 2) = v;
    }
  }
}

// ---------------- kernel 4: split-KV(x8) flash attention ----------------
// grid 1024 = 8p x 4b x 32qt; 128 q/block, 8 waves x 16 q. KVBLK=32, dbuf gll staging.
// Swapped QK^T, log2-domain softmax, defer-max, shfl lane exchange (R4-proven).
// Writes NORMALIZED partial O^T fp16 [pb][d][n] + per-query (m, l) f32.
#define ATT_LDS 32768
__global__ __launch_bounds__(512, 8) void k_attn_part(const _Float16* __restrict__ qkvt,
                                                      const _Float16* __restrict__ vt,
                                                      _Float16* __restrict__ opart,
                                                      float* __restrict__ mlm,
                                                      float* __restrict__ mll)
{
  extern __shared__ char smem[];                     // buf*16K: K[32][256B] ; +8K: V[128][64B]
  const int t = threadIdx.x, lane = t & 63, w = t >> 6;  // w 0..7
  const int lo = lane & 15, hi = lane >> 4;
  const int id = blockIdx.x;
  const int vid = (id & 7) * 128 + (id >> 3);        // XCD x gets bp in {4x..4x+3}
  const int qt = vid & 31, bp = vid >> 5;
  const int b = bp >> 3, p = bp & 7;
  const int n0 = qt * 128;
  const char* qbase = (const char*)qkvt + (size_t)b * 4096 * 768;
  const char* vbase = (const char*)vt + (size_t)b * 128 * 8192;

  // Q B-fragments from global (one-time; log2e folded upstream)
  h8 bq[4];
  {
    const char* qr = qbase + (size_t)(n0 + w * 16 + lo) * 768;
    #pragma unroll
    for (int dk = 0; dk < 4; ++dk) bq[dk] = *(const h8*)(qr + dk * 64 + hi * 16);
  }

  // per-lane staging offsets (source pre-swizzled; LDS dest linear). One K + one V gll per thread.
  int koff, voff;
  const int kdst = w * 1024;
  {
    int krow = w * 4 + (lane >> 4);
    koff = krow * 768 + 256 + (((lane & 15) * 16) ^ ((krow & 7) << 4));
    int d = w * 16 + (lane >> 2);
    voff = d * 64 + (((lane & 3) * 16) ^ (((lane >> 3) & 3) << 4));
  }

  auto stage = [&](int m0, int buf) {
    char* kb = smem + buf * 16384;
    char* vb = kb + 8192;
    gll16(qbase + (size_t)m0 * 768 + koff, kb + kdst);
    gll16(vbase + (size_t)m0 * 2 + ((voff >> 6) << 13) + (voff & 63), vb + kdst);
  };

  const f32x4 zero4 = {0.f, 0.f, 0.f, 0.f};
  float m_run = -1e30f, l_run = 0.f;                 // l_run: per-lane partial (own 8 keys)
  f32x4 oacc[8];
  #pragma unroll
  for (int dt = 0; dt < 8; ++dt) oacc[dt] = zero4;

  const int slA = (hi & 1) * 32 + lo, slB = slA + 16;
  const bool up = (hi & 2) != 0;

  stage(p * 512, 0);
  __syncthreads();

  for (int it = 0; it < 16; ++it) {
    const int buf = it & 1;
    if (it < 15) stage(p * 512 + (it + 1) * 32, buf ^ 1);

    const char* kb = smem + buf * 16384;
    const char* vb = kb + 8192;

    // ---- S^T = K Q (log2 domain) ----
    f32x4 s[2];
    s[0] = zero4; s[1] = zero4;
    __builtin_amdgcn_s_setprio(1);
    #pragma unroll
    for (int mt = 0; mt < 2; ++mt) {
      #pragma unroll
      for (int dk = 0; dk < 4; ++dk) {
        int row = mt * 16 + lo;
        h8 ak = *(const h8*)(kb + row * 256 + ((dk * 64 + hi * 16) ^ ((row & 7) << 4)));
        s[mt] = __builtin_amdgcn_mfma_f32_16x16x32_f16(ak, bq[dk], s[mt], 0, 0, 0);
      }
    }
    __builtin_amdgcn_s_setprio(0);

    // ---- online softmax, defer-max THR=8 ----
    float mx = fmaxf(fmaxf(fmaxf(s[0][0], s[0][1]), fmaxf(s[0][2], s[0][3])),
                     fmaxf(fmaxf(s[1][0], s[1][1]), fmaxf(s[1][2], s[1][3])));
    mx = fmaxf(mx, __shfl_xor(mx, 16));
    mx = fmaxf(mx, __shfl_xor(mx, 32));
    if (mx > m_run + 8.f) {                          // rare after first iters
      float scn = EXP2(m_run - mx);
      m_run = mx;
      l_run *= scn;
      #pragma unroll
      for (int dt = 0; dt < 8; ++dt) oacc[dt] *= scn;
    }
    uint32_t pk[2][2];
    float rs = 0.f;
    #pragma unroll
    for (int mt = 0; mt < 2; ++mt) {
      float p0 = EXP2(s[mt][0] - m_run), p1 = EXP2(s[mt][1] - m_run);
      float p2 = EXP2(s[mt][2] - m_run), p3 = EXP2(s[mt][3] - m_run);
      rs += (p0 + p1) + (p2 + p3);
      pk[mt][0] = __builtin_bit_cast(uint32_t, __builtin_amdgcn_cvt_pkrtz(p0, p1));
      pk[mt][1] = __builtin_bit_cast(uint32_t, __builtin_amdgcn_cvt_pkrtz(p2, p3));
    }
    l_run += rs;

    // ---- build P^T B-fragment via lane exchange: keys hi*8..hi*8+7 for query lo ----
    uint32_t w0a = __shfl(pk[0][0], slA), w0b = __shfl(pk[1][0], slA);
    uint32_t w1a = __shfl(pk[0][1], slA), w1b = __shfl(pk[1][1], slA);
    uint32_t w2a = __shfl(pk[0][0], slB), w2b = __shfl(pk[1][0], slB);
    uint32_t w3a = __shfl(pk[0][1], slB), w3b = __shfl(pk[1][1], slB);
    u32x4 bw = { up ? w0b : w0a, up ? w1b : w1a, up ? w2b : w2a, up ? w3b : w3a };
    h8 bpf = __builtin_bit_cast(h8, bw);

    // ---- O^T += V^T P^T ----
    __builtin_amdgcn_s_setprio(1);
    #pragma unroll
    for (int dt = 0; dt < 8; ++dt) {
      int d = dt * 16 + lo;
      h8 av = *(const h8*)(vb + d * 64 + ((hi * 16) ^ (((lo >> 1) & 3) << 4)));
      oacc[dt] = __builtin_amdgcn_mfma_f32_16x16x32_f16(av, bpf, oacc[dt], 0, 0, 0);
    }
    __builtin_amdgcn_s_setprio(0);

    if (it < 15) __syncthreads();
  }

  // ---- finalize: reduce l across hi-groups, store normalized fp16 partial + (m,l) ----
  l_run += __shfl_xor(l_run, 16);
  l_run += __shfl_xor(l_run, 32);
  float invl = 1.0f / l_run;
  _Float16* oph = opart + ((size_t)(p * 4 + b) * 128) * 4096;
  const int ncol = n0 + w * 16 + lo;
  #pragma unroll
  for (int dt = 0; dt < 8; ++dt)
    #pragma unroll
    for (int r = 0; r < 4; ++r) {
      int d = dt * 16 + hi * 4 + r;
      oph[(size_t)d * 4096 + ncol] = (_Float16)(oacc[dt][r] * invl);
    }
  if (hi == 0) {
    size_t mlbase = (size_t)(p * 4 + b) * 4096 + ncol;
    mlm[mlbase] = m_run;
    mll[mlbase] = l_run;
  }
}

// ---------------- kernel 5: combine 8 normalized KV-partials ----------------
__global__ void k_reduce(const _Float16* __restrict__ opart, const float* __restrict__ mlm,
                         const float* __restrict__ mll, float* __restrict__ out)
{
  int idx = blockIdx.x * 256 + threadIdx.x;          // 4b*128d*1024(n/4)
  int n4 = idx & 1023, d = (idx >> 10) & 127, b = idx >> 17;
  int n0 = n4 * 4;
  f32x4 m[8], lv[8];
  #pragma unroll
  for (int p = 0; p < 8; ++p) {
    size_t mb = (size_t)(p * 4 + b) * 4096 + n0;
    m[p]  = *(const f32x4*)(mlm + mb);
    lv[p] = *(const f32x4*)(mll + mb);
  }
  f32x4 M = m[0];
  #pragma unroll
  for (int p = 1; p < 8; ++p)
    #pragma unroll
    for (int j = 0; j < 4; ++j) M[j] = fmaxf(M[j], m[p][j]);
  f32x4 denom = {0.f, 0.f, 0.f, 0.f}, num = {0.f, 0.f, 0.f, 0.f};
  #pragma unroll
  for (int p = 0; p < 8; ++p) {
    h4 o = *(const h4*)(opart + ((size_t)((p * 4 + b) * 128 + d)) * 4096 + n0);
    #pragma unroll
    for (int j = 0; j < 4; ++j) {
      float wgt = lv[p][j] * EXP2(m[p][j] - M[j]);
      denom[j] += wgt;
      num[j]   += (float)o[j] * wgt;
    }
  }
  f32x4 r;
  #pragma unroll
  for (int j = 0; j < 4; ++j) r[j] = num[j] / denom[j];
  *(f32x4*)(out + ((size_t)(b * 128 + d)) * 4096 + n0) = r;
}

extern "C" void kernel_launch(void* const* d_in, const int* in_sizes, int n_in,
                              void* d_out, int out_size, void* d_ws, size_t ws_size,
                              hipStream_t stream)
{
  const float* feats = (const float*)d_in[0];
  const float* pw = (const float*)d_in[1];
  const float* pb = (const float*)d_in[2];
  const float* w1 = (const float*)d_in[3];
  const float* b1 = (const float*)d_in[4];
  const float* w2 = (const float*)d_in[5];
  const float* b2 = (const float*)d_in[6];
  const float* w3 = (const float*)d_in[7];
  const float* b3 = (const float*)d_in[8];
  char* ws = (char*)d_ws;
  _Float16* PWh = (_Float16*)(ws + WS_PWH);
  _Float16* Wh = (_Float16*)(ws + WS_WH);
  float* bc = (float*)(ws + WS_BC);
  char* ftbase = ws + WS_FT;
  _Float16* FT = (_Float16*)(ws + WS_FT);
  _Float16* qkvt = (_Float16*)(ws + WS_QKVT);
  _Float16* vt = (_Float16*)(ws + WS_VT);
  _Float16* opart = (_Float16*)(ws + WS_OP);
  float* mlm = (float*)(ws + WS_MLM);
  float* mll = (float*)(ws + WS_MLL);
  float* out = (float*)d_out;

  hipLaunchKernelGGL(k_cvt, dim3(704), dim3(256), 0, stream,
                     pw, pb, w1, b1, w2, b2, w3, b3, PWh, Wh, bc);
  hipLaunchKernelGGL(k_featT, dim3(16, 64, 4), dim3(256), 0, stream, feats, FT);
  hipLaunchKernelGGL(k_gemm1, dim3(64, 4), dim3(256), 49152, stream, ftbase, PWh);
  hipLaunchKernelGGL(k_gemm2, dim3(3, 32, 4), dim3(256), 65536, stream, ftbase, Wh, bc, qkvt, vt);
  hipLaunchKernelGGL(k_attn_part, dim3(1024), dim3(512), ATT_LDS, stream, qkvt, vt, opart, mlm, mll);
  hipLaunchKernelGGL(k_reduce, dim3(2048), dim3(256), 0, stream, opart, mlm, mll, out);
}

// Round 7
// 146.817 us; speedup vs baseline: 1.9180x; 1.9180x over previous
//
#include <hip/hip_runtime.h>
#include <stdint.h>

typedef _Float16 h8 __attribute__((ext_vector_type(8)));
typedef _Float16 h4 __attribute__((ext_vector_type(4)));
typedef float f32x4 __attribute__((ext_vector_type(4)));
typedef uint32_t u32x4 __attribute__((ext_vector_type(4)));

#if __has_builtin(__builtin_amdgcn_exp2f)
#define EXP2(x) __builtin_amdgcn_exp2f(x)
#else
#define EXP2(x) exp2f(x)
#endif

// workspace map (<= 51380224 bytes)
#define WS_PWH  0u          // _Float16 [128][1024]  (dead after gemm1; mlm overwrites)
#define WS_WH   262144u     // _Float16 [384][128]   (dead after gemm2; mll overwrites)
#define WS_BC   600064u     // float [384]
#define WS_FT   1048576u    // _Float16 [4][4096][1024] feats^T; F2D aliases first 256B of rows
#define WS_QKVT 34603008u   // _Float16 [4][4096][384] q|k|v, n-major (v slice unused)
#define WS_VT   47185920u   // _Float16 [4][128][4096] v, d-major
#define WS_OP   WS_FT       // _Float16 [32 pb][128 d][4096 n] normalized partial O
#define WS_MLM  0u          // float [32][4096] running max (log2 domain)
#define WS_MLL  524288u     // float [32][4096] running sum

__device__ __forceinline__ void gll16(const void* g, void* l) {
  __builtin_amdgcn_global_load_lds((const __attribute__((address_space(1))) unsigned int*)g,
                                   (__attribute__((address_space(3))) unsigned int*)l, 16, 0, 0);
}

// ---------------- kernel 0: casts + combined bias bc = b + W*pb; q-weights scaled by log2(e) ----------------
__global__ void k_cvt(const float* __restrict__ pw, const float* __restrict__ pb,
                      const float* __restrict__ w1, const float* __restrict__ b1,
                      const float* __restrict__ w2, const float* __restrict__ b2,
                      const float* __restrict__ w3, const float* __restrict__ b3,
                      _Float16* __restrict__ PWh, _Float16* __restrict__ Wh,
                      float* __restrict__ bc)
{
  const float LOG2E = 1.4426950408889634f;
  int idx = blockIdx.x * 256 + threadIdx.x;
  if (idx < 131072) {
    PWh[idx] = (_Float16)pw[idx];
  } else {
    int j = idx - 131072;
    if (j < 49152) {
      int g = j >> 14, rem = j & 16383;
      const float* wg = (g == 0) ? w1 : (g == 1 ? w2 : w3);
      float v = wg[rem];
      if (g == 0) v *= LOG2E;                        // q in log2 domain
      Wh[j] = (_Float16)v;
    }
  }
  if (idx < 384) {
    int g = idx >> 7, o = idx & 127;
    const float* wg = (g == 0) ? w1 : (g == 1 ? w2 : w3);
    const float* bg = (g == 0) ? b1 : (g == 1 ? b2 : b3);
    float s = bg[o];
    for (int c = 0; c < 128; ++c) s += wg[o * 128 + c] * pb[c];
    if (g == 0) s *= LOG2E;
    bc[idx] = s;
  }
}

// ---------------- kernel 1: feats (b,1024,4096) f32 -> feats^T (b,4096,1024) fp16 ----------------
__global__ void k_featT(const float* __restrict__ feats, _Float16* __restrict__ FT)
{
  __shared__ float tile[64][65];
  const int ck0 = blockIdx.x * 64, n0 = blockIdx.y * 64, b = blockIdx.z;
  const int t = threadIdx.x;
  const float* src = feats + ((size_t)(b * 1024 + ck0)) * 4096 + n0;
  #pragma unroll
  for (int p = 0; p < 4; ++p) {
    int i = t + p * 256, row = i >> 4, slot = i & 15;
    float4 g = *(const float4*)(src + (size_t)row * 4096 + slot * 4);
    tile[row][slot * 4 + 0] = g.x; tile[row][slot * 4 + 1] = g.y;
    tile[row][slot * 4 + 2] = g.z; tile[row][slot * 4 + 3] = g.w;
  }
  __syncthreads();
  _Float16* dst = FT + ((size_t)(b * 4096 + n0)) * 1024 + ck0;
  #pragma unroll
  for (int p = 0; p < 4; ++p) {
    int i = t + p * 256, n = i >> 4, cs = i & 15;
    h4 o;
    #pragma unroll
    for (int j = 0; j < 4; ++j) o[j] = (_Float16)tile[cs * 4 + j][n];
    *(h4*)(dst + (size_t)n * 1024 + cs * 4) = o;
  }
}

// ---------------- kernel 2: GEMM1  F2D[b][n][128] = FT[b][n][:] . PWh[o][:] ----------------
__global__ __launch_bounds__(256) void k_gemm1(char* __restrict__ ftbase,
                                               const _Float16* __restrict__ PWh)
{
  extern __shared__ char smem[];                     // 2 bufs x (A 8K + B 16K) = 48K
  const int t = threadIdx.x, lane = t & 63, w = t >> 6;
  const int lo = lane & 15, hi = lane >> 4;
  const int n0 = blockIdx.x * 64, b = blockIdx.y;
  const int wr = w >> 1, wc = w & 1;
  const int nb = wr * 32, ob = wc * 64;

  uint4 areg[2], wreg[4];
  const char* Fbase = ftbase + ((size_t)(b * 4096 + n0)) * 2048;
  const char* Wbase = (const char*)PWh;

  auto stageload = [&](int s) {
    #pragma unroll
    for (int p = 0; p < 2; ++p) {
      int i = t + p * 256, row = i >> 3, slot = i & 7;
      areg[p] = *(const uint4*)(Fbase + (size_t)row * 2048 + s * 128 + slot * 16);
    }
    #pragma unroll
    for (int p = 0; p < 4; ++p) {
      int i = t + p * 256, row = i >> 3, slot = i & 7;
      wreg[p] = *(const uint4*)(Wbase + (size_t)row * 2048 + s * 128 + slot * 16);
    }
  };
  auto stagewrite = [&](int buf) {
    char* base = smem + buf * 24576;
    #pragma unroll
    for (int p = 0; p < 2; ++p) {
      int i = t + p * 256, row = i >> 3, slot = i & 7;
      *(uint4*)(base + row * 128 + ((slot * 16) ^ ((row & 7) << 4))) = areg[p];
    }
    #pragma unroll
    for (int p = 0; p < 4; ++p) {
      int i = t + p * 256, row = i >> 3, slot = i & 7;
      *(uint4*)(base + 8192 + row * 128 + ((slot * 16) ^ ((row & 7) << 4))) = wreg[p];
    }
  };

  const f32x4 zero4 = {0.f, 0.f, 0.f, 0.f};
  f32x4 acc[2][4];
  #pragma unroll
  for (int i2 = 0; i2 < 2; ++i2)
    #pragma unroll
    for (int j2 = 0; j2 < 4; ++j2) acc[i2][j2] = zero4;

  stageload(0); stagewrite(0);
  for (int s = 0; s < 16; ++s) {
    __syncthreads();
    if (s < 15) stageload(s + 1);
    const char* base = smem + (s & 1) * 24576;
    #pragma unroll
    for (int kk = 0; kk < 2; ++kk) {
      const int cb = kk * 64 + hi * 16;
      h8 af[2], bf[4];
      #pragma unroll
      for (int i2 = 0; i2 < 2; ++i2) {
        int row = nb + i2 * 16 + lo;
        af[i2] = *(const h8*)(base + row * 128 + (cb ^ ((row & 7) << 4)));
      }
      #pragma unroll
      for (int j2 = 0; j2 < 4; ++j2) {
        int row = ob + j2 * 16 + lo;
        bf[j2] = *(const h8*)(base + 8192 + row * 128 + (cb ^ ((row & 7) << 4)));
      }
      #pragma unroll
      for (int i2 = 0; i2 < 2; ++i2)
        #pragma unroll
        for (int j2 = 0; j2 < 4; ++j2)
          acc[i2][j2] = __builtin_amdgcn_mfma_f32_16x16x32_f16(af[i2], bf[j2], acc[i2][j2], 0, 0, 0);
    }
    if (s < 15) stagewrite((s + 1) & 1);
  }

  #pragma unroll
  for (int i2 = 0; i2 < 2; ++i2)
    #pragma unroll
    for (int j2 = 0; j2 < 4; ++j2)
      #pragma unroll
      for (int r = 0; r < 4; ++r) {
        int n = n0 + nb + i2 * 16 + hi * 4 + r;
        int o = ob + j2 * 16 + lo;
        *(_Float16*)(ftbase + ((size_t)(b * 4096 + n)) * 2048 + o * 2) = (_Float16)acc[i2][j2][r];
      }
}

// ---------------- kernel 3: GEMM2  qkvt = F2D . Wh + bc; v-group (bx==2) goes to vt via LDS bounce ----------------
__global__ void k_gemm2(const char* __restrict__ ftbase, const _Float16* __restrict__ Wh,
                        const float* __restrict__ bc, _Float16* __restrict__ qkvt,
                        _Float16* __restrict__ vt)
{
  extern __shared__ char smem[];                     // A 32K + B 32K; bx==2 reuses for vtile
  const int t = threadIdx.x, lane = t & 63, w = t >> 6;
  const int lo = lane & 15, hi = lane >> 4;
  const int bx = blockIdx.x, n0 = blockIdx.y * 128, b = blockIdx.z;
  const int wr = w >> 1, wc = w & 1;
  const int nb = wr * 64, ob = wc * 64;

  #pragma unroll
  for (int q = 0; q < 8; ++q) {
    int c = w * 8 + q;
    int row = c * 4 + (lane >> 4);
    int col = ((lane & 15) * 16) ^ ((row & 7) << 4);
    gll16(ftbase + ((size_t)(b * 4096 + n0 + row)) * 2048 + col, smem + c * 1024);
    gll16((const char*)Wh + (size_t)(bx * 128 + row) * 256 + col, smem + 32768 + c * 1024);
  }
  __syncthreads();

  const f32x4 zero4 = {0.f, 0.f, 0.f, 0.f};
  f32x4 acc[4][4];
  #pragma unroll
  for (int i2 = 0; i2 < 4; ++i2)
    #pragma unroll
    for (int j2 = 0; j2 < 4; ++j2) acc[i2][j2] = zero4;

  #pragma unroll
  for (int kk = 0; kk < 4; ++kk) {
    const int cb = kk * 64 + hi * 16;
    h8 af[4], bf[4];
    #pragma unroll
    for (int i2 = 0; i2 < 4; ++i2) {
      int row = nb + i2 * 16 + lo;
      af[i2] = *(const h8*)(smem + row * 256 + (cb ^ ((row & 7) << 4)));
    }
    #pragma unroll
    for (int j2 = 0; j2 < 4; ++j2) {
      int row = ob + j2 * 16 + lo;
      bf[j2] = *(const h8*)(smem + 32768 + row * 256 + (cb ^ ((row & 7) << 4)));
    }
    #pragma unroll
    for (int i2 = 0; i2 < 4; ++i2)
      #pragma unroll
      for (int j2 = 0; j2 < 4; ++j2)
        acc[i2][j2] = __builtin_amdgcn_mfma_f32_16x16x32_f16(af[i2], bf[j2], acc[i2][j2], 0, 0, 0);
  }

  if (bx < 2) {
    #pragma unroll
    for (int j2 = 0; j2 < 4; ++j2) {
      int o = bx * 128 + ob + j2 * 16 + lo;
      float bias = bc[o];
      #pragma unroll
      for (int i2 = 0; i2 < 4; ++i2)
        #pragma unroll
        for (int r = 0; r < 4; ++r) {
          int n = n0 + nb + i2 * 16 + hi * 4 + r;
          qkvt[((size_t)(b * 4096 + n)) * 384 + o] = (_Float16)(acc[i2][j2][r] + bias);
        }
    }
  } else {
    // v-group: bounce through LDS (padded stride 272B) and store transposed to vt[b][d][m]
    __syncthreads();                                 // A/B reads done; reuse smem
    #pragma unroll
    for (int j2 = 0; j2 < 4; ++j2) {
      int o = ob + j2 * 16 + lo;                     // d = o (local 0..127)
      float bias = bc[256 + o];
      #pragma unroll
      for (int i2 = 0; i2 < 4; ++i2) {
        int nl = nb + i2 * 16 + hi * 4;
        h4 v4;
        #pragma unroll
        for (int r = 0; r < 4; ++r) v4[r] = (_Float16)(acc[i2][j2][r] + bias);
        *(h4*)(smem + o * 272 + nl * 2) = v4;
      }
    }
    __syncthreads();
    #pragma unroll
    for (int p2 = 0; p2 < 8; ++p2) {
      int i = t + p2 * 256, d = i >> 4, ch = i & 15;
      uint4 v = *(const uint4*)(smem + d * 272 + ch * 16);
      *(uint4*)((char*)vt + ((size_t)(b * 128 + d)) * 8192 + (n0 + ch * 8) * 2) = v;
    }
  }
}

// ---------------- kernel 4: split-KV(x8) flash attention ----------------
// grid 1024 = 8p x 4b x 32qt; 128 q/block, 8 waves x 16 q. KVBLK=32, dbuf gll staging.
// Swapped QK^T, log2-domain softmax, defer-max, shfl lane exchange (R4-proven).
// launch_bounds (512,4): VGPR cap 128 >= ~95 live regs -> NO SPILL (R6's (512,8) cap=64 spilled
// the accumulators to scratch: 475MB FETCH/dispatch, 200us. Occupancy 2 blocks/CU is enough.)
#define ATT_LDS 32768
__global__ __launch_bounds__(512, 4) void k_attn_part(const _Float16* __restrict__ qkvt,
                                                      const _Float16* __restrict__ vt,
                                                      _Float16* __restrict__ opart,
                                                      float* __restrict__ mlm,
                                                      float* __restrict__ mll)
{
  extern __shared__ char smem[];                     // buf*16K: K[32][256B] ; +8K: V[128][64B]
  const int t = threadIdx.x, lane = t & 63, w = t >> 6;  // w 0..7
  const int lo = lane & 15, hi = lane >> 4;
  const int id = blockIdx.x;
  const int vid = (id & 7) * 128 + (id >> 3);        // XCD x gets bp in {4x..4x+3}
  const int qt = vid & 31, bp = vid >> 5;
  const int b = bp >> 3, p = bp & 7;
  const int n0 = qt * 128;
  const char* qbase = (const char*)qkvt + (size_t)b * 4096 * 768;
  const char* vbase = (const char*)vt + (size_t)b * 128 * 8192;

  // Q B-fragments from global (one-time; log2e folded upstream)
  h8 bq[4];
  {
    const char* qr = qbase + (size_t)(n0 + w * 16 + lo) * 768;
    #pragma unroll
    for (int dk = 0; dk < 4; ++dk) bq[dk] = *(const h8*)(qr + dk * 64 + hi * 16);
  }

  // per-lane staging offsets (source pre-swizzled; LDS dest linear). One K + one V gll per thread.
  int koff, voff;
  const int kdst = w * 1024;
  {
    int krow = w * 4 + (lane >> 4);
    koff = krow * 768 + 256 + (((lane & 15) * 16) ^ ((krow & 7) << 4));
    int d = w * 16 + (lane >> 2);
    voff = d * 64 + (((lane & 3) * 16) ^ (((lane >> 3) & 3) << 4));
  }

  auto stage = [&](int m0, int buf) {
    char* kb = smem + buf * 16384;
    char* vb = kb + 8192;
    gll16(qbase + (size_t)m0 * 768 + koff, kb + kdst);
    gll16(vbase + (size_t)m0 * 2 + ((voff >> 6) << 13) + (voff & 63), vb + kdst);
  };

  const f32x4 zero4 = {0.f, 0.f, 0.f, 0.f};
  float m_run = -1e30f, l_run = 0.f;                 // l_run: per-lane partial (own 8 keys)
  f32x4 oacc[8];
  #pragma unroll
  for (int dt = 0; dt < 8; ++dt) oacc[dt] = zero4;

  const int slA = (hi & 1) * 32 + lo, slB = slA + 16;
  const bool up = (hi & 2) != 0;

  stage(p * 512, 0);
  __syncthreads();

  for (int it = 0; it < 16; ++it) {
    const int buf = it & 1;
    if (it < 15) stage(p * 512 + (it + 1) * 32, buf ^ 1);

    const char* kb = smem + buf * 16384;
    const char* vb = kb + 8192;

    // ---- S^T = K Q (log2 domain) ----
    f32x4 s[2];
    s[0] = zero4; s[1] = zero4;
    __builtin_amdgcn_s_setprio(1);
    #pragma unroll
    for (int mt = 0; mt < 2; ++mt) {
      #pragma unroll
      for (int dk = 0; dk < 4; ++dk) {
        int row = mt * 16 + lo;
        h8 ak = *(const h8*)(kb + row * 256 + ((dk * 64 + hi * 16) ^ ((row & 7) << 4)));
        s[mt] = __builtin_amdgcn_mfma_f32_16x16x32_f16(ak, bq[dk], s[mt], 0, 0, 0);
      }
    }
    __builtin_amdgcn_s_setprio(0);

    // ---- online softmax, defer-max THR=8 ----
    float mx = fmaxf(fmaxf(fmaxf(s[0][0], s[0][1]), fmaxf(s[0][2], s[0][3])),
                     fmaxf(fmaxf(s[1][0], s[1][1]), fmaxf(s[1][2], s[1][3])));
    mx = fmaxf(mx, __shfl_xor(mx, 16));
    mx = fmaxf(mx, __shfl_xor(mx, 32));
    if (mx > m_run + 8.f) {                          // rare after first iters
      float scn = EXP2(m_run - mx);
      m_run = mx;
      l_run *= scn;
      #pragma unroll
      for (int dt = 0; dt < 8; ++dt) oacc[dt] *= scn;
    }
    uint32_t pk[2][2];
    float rs = 0.f;
    #pragma unroll
    for (int mt = 0; mt < 2; ++mt) {
      float p0 = EXP2(s[mt][0] - m_run), p1 = EXP2(s[mt][1] - m_run);
      float p2 = EXP2(s[mt][2] - m_run), p3 = EXP2(s[mt][3] - m_run);
      rs += (p0 + p1) + (p2 + p3);
      pk[mt][0] = __builtin_bit_cast(uint32_t, __builtin_amdgcn_cvt_pkrtz(p0, p1));
      pk[mt][1] = __builtin_bit_cast(uint32_t, __builtin_amdgcn_cvt_pkrtz(p2, p3));
    }
    l_run += rs;

    // ---- build P^T B-fragment via lane exchange: keys hi*8..hi*8+7 for query lo ----
    uint32_t w0a = __shfl(pk[0][0], slA), w0b = __shfl(pk[1][0], slA);
    uint32_t w1a = __shfl(pk[0][1], slA), w1b = __shfl(pk[1][1], slA);
    uint32_t w2a = __shfl(pk[0][0], slB), w2b = __shfl(pk[1][0], slB);
    uint32_t w3a = __shfl(pk[0][1], slB), w3b = __shfl(pk[1][1], slB);
    u32x4 bw = { up ? w0b : w0a, up ? w1b : w1a, up ? w2b : w2a, up ? w3b : w3a };
    h8 bpf = __builtin_bit_cast(h8, bw);

    // ---- O^T += V^T P^T ----
    __builtin_amdgcn_s_setprio(1);
    #pragma unroll
    for (int dt = 0; dt < 8; ++dt) {
      int d = dt * 16 + lo;
      h8 av = *(const h8*)(vb + d * 64 + ((hi * 16) ^ (((lo >> 1) & 3) << 4)));
      oacc[dt] = __builtin_amdgcn_mfma_f32_16x16x32_f16(av, bpf, oacc[dt], 0, 0, 0);
    }
    __builtin_amdgcn_s_setprio(0);

    if (it < 15) __syncthreads();
  }

  // ---- finalize: reduce l across hi-groups, store normalized fp16 partial + (m,l) ----
  l_run += __shfl_xor(l_run, 16);
  l_run += __shfl_xor(l_run, 32);
  float invl = 1.0f / l_run;
  _Float16* oph = opart + ((size_t)(p * 4 + b) * 128) * 4096;
  const int ncol = n0 + w * 16 + lo;
  #pragma unroll
  for (int dt = 0; dt < 8; ++dt)
    #pragma unroll
    for (int r = 0; r < 4; ++r) {
      int d = dt * 16 + hi * 4 + r;
      oph[(size_t)d * 4096 + ncol] = (_Float16)(oacc[dt][r] * invl);
    }
  if (hi == 0) {
    size_t mlbase = (size_t)(p * 4 + b) * 4096 + ncol;
    mlm[mlbase] = m_run;
    mll[mlbase] = l_run;
  }
}

// ---------------- kernel 5: combine 8 normalized KV-partials ----------------
__global__ void k_reduce(const _Float16* __restrict__ opart, const float* __restrict__ mlm,
                         const float* __restrict__ mll, float* __restrict__ out)
{
  int idx = blockIdx.x * 256 + threadIdx.x;          // 4b*128d*1024(n/4)
  int n4 = idx & 1023, d = (idx >> 10) & 127, b = idx >> 17;
  int n0 = n4 * 4;
  f32x4 m[8], lv[8];
  #pragma unroll
  for (int p = 0; p < 8; ++p) {
    size_t mb = (size_t)(p * 4 + b) * 4096 + n0;
    m[p]  = *(const f32x4*)(mlm + mb);
    lv[p] = *(const f32x4*)(mll + mb);
  }
  f32x4 M = m[0];
  #pragma unroll
  for (int p = 1; p < 8; ++p)
    #pragma unroll
    for (int j = 0; j < 4; ++j) M[j] = fmaxf(M[j], m[p][j]);
  f32x4 denom = {0.f, 0.f, 0.f, 0.f}, num = {0.f, 0.f, 0.f, 0.f};
  #pragma unroll
  for (int p = 0; p < 8; ++p) {
    h4 o = *(const h4*)(opart + ((size_t)((p * 4 + b) * 128 + d)) * 4096 + n0);
    #pragma unroll
    for (int j = 0; j < 4; ++j) {
      float wgt = lv[p][j] * EXP2(m[p][j] - M[j]);
      denom[j] += wgt;
      num[j]   += (float)o[j] * wgt;
    }
  }
  f32x4 r;
  #pragma unroll
  for (int j = 0; j < 4; ++j) r[j] = num[j] / denom[j];
  *(f32x4*)(out + ((size_t)(b * 128 + d)) * 4096 + n0) = r;
}

extern "C" void kernel_launch(void* const* d_in, const int* in_sizes, int n_in,
                              void* d_out, int out_size, void* d_ws, size_t ws_size,
                              hipStream_t stream)
{
  const float* feats = (const float*)d_in[0];
  const float* pw = (const float*)d_in[1];
  const float* pb = (const float*)d_in[2];
  const float* w1 = (const float*)d_in[3];
  const float* b1 = (const float*)d_in[4];
  const float* w2 = (const float*)d_in[5];
  const float* b2 = (const float*)d_in[6];
  const float* w3 = (const float*)d_in[7];
  const float* b3 = (const float*)d_in[8];
  char* ws = (char*)d_ws;
  _Float16* PWh = (_Float16*)(ws + WS_PWH);
  _Float16* Wh = (_Float16*)(ws + WS_WH);
  float* bc = (float*)(ws + WS_BC);
  char* ftbase = ws + WS_FT;
  _Float16* FT = (_Float16*)(ws + WS_FT);
  _Float16* qkvt = (_Float16*)(ws + WS_QKVT);
  _Float16* vt = (_Float16*)(ws + WS_VT);
  _Float16* opart = (_Float16*)(ws + WS_OP);
  float* mlm = (float*)(ws + WS_MLM);
  float* mll = (float*)(ws + WS_MLL);
  float* out = (float*)d_out;

  hipLaunchKernelGGL(k_cvt, dim3(704), dim3(256), 0, stream,
                     pw, pb, w1, b1, w2, b2, w3, b3, PWh, Wh, bc);
  hipLaunchKernelGGL(k_featT, dim3(16, 64, 4), dim3(256), 0, stream, feats, FT);
  hipLaunchKernelGGL(k_gemm1, dim3(64, 4), dim3(256), 49152, stream, ftbase, PWh);
  hipLaunchKernelGGL(k_gemm2, dim3(3, 32, 4), dim3(256), 65536, stream, ftbase, Wh, bc, qkvt, vt);
  hipLaunchKernelGGL(k_attn_part, dim3(1024), dim3(512), ATT_LDS, stream, qkvt, vt, opart, mlm, mll);
  hipLaunchKernelGGL(k_reduce, dim3(2048), dim3(256), 0, stream, opart, mlm, mll, out);
}

// Round 8
// 108.050 us; speedup vs baseline: 2.6062x; 1.3588x over previous
//
#include <hip/hip_runtime.h>
#include <stdint.h>

typedef _Float16 h8 __attribute__((ext_vector_type(8)));
typedef _Float16 h4 __attribute__((ext_vector_type(4)));
typedef float f32x4 __attribute__((ext_vector_type(4)));
typedef uint32_t u32x4 __attribute__((ext_vector_type(4)));

#if __has_builtin(__builtin_amdgcn_exp2f)
#define EXP2(x) __builtin_amdgcn_exp2f(x)
#else
#define EXP2(x) exp2f(x)
#endif

// workspace map (total exactly 51380224 bytes)
#define WS_PWH  0u          // _Float16 [128][1024]  (dead after fg1; mlm overwrites)
#define WS_WH   262144u     // _Float16 [384][128]   (dead after gemm2; mlm/mll overwrite)
#define WS_BC   600064u     // float [384]           (dead after gemm2)
#define WS_F2D  1048576u    // _Float16 [4][4096][128] dense (dead after gemm2)
#define WS_OP   5242880u    // _Float16 [32 pb][128 d][4096 n] normalized partial O
#define WS_QKVT 38797312u   // _Float16 [4][4096][256] q|k, 512B rows
#define WS_VT   47185920u   // _Float16 [4][128][4096] v, d-major
#define WS_MLM  0u          // float [32][4096] running max (log2 domain)
#define WS_MLL  524288u     // float [32][4096] running sum

__device__ __forceinline__ void gll16(const void* g, void* l) {
  __builtin_amdgcn_global_load_lds((const __attribute__((address_space(1))) unsigned int*)g,
                                   (__attribute__((address_space(3))) unsigned int*)l, 16, 0, 0);
}

// ---------------- kernel 0: casts + combined bias bc = b + W*pb; q-weights scaled by log2(e) ----------------
__global__ void k_cvt(const float* __restrict__ pw, const float* __restrict__ pb,
                      const float* __restrict__ w1, const float* __restrict__ b1,
                      const float* __restrict__ w2, const float* __restrict__ b2,
                      const float* __restrict__ w3, const float* __restrict__ b3,
                      _Float16* __restrict__ PWh, _Float16* __restrict__ Wh,
                      float* __restrict__ bc)
{
  const float LOG2E = 1.4426950408889634f;
  int idx = blockIdx.x * 256 + threadIdx.x;
  if (idx < 131072) {
    PWh[idx] = (_Float16)pw[idx];
  } else {
    int j = idx - 131072;
    if (j < 49152) {
      int g = j >> 14, rem = j & 16383;
      const float* wg = (g == 0) ? w1 : (g == 1 ? w2 : w3);
      float v = wg[rem];
      if (g == 0) v *= LOG2E;                        // q in log2 domain
      Wh[j] = (_Float16)v;
    }
  }
  if (idx < 384) {
    int g = idx >> 7, o = idx & 127;
    const float* wg = (g == 0) ? w1 : (g == 1 ? w2 : w3);
    const float* bg = (g == 0) ? b1 : (g == 1 ? b2 : b3);
    float s = bg[o];
    for (int c = 0; c < 128; ++c) s += wg[o * 128 + c] * pb[c];
    if (g == 0) s *= LOG2E;
    bc[idx] = s;
  }
}

// ---------------- kernel 1: FUSED featT + gemm1 ----------------
// F2D[b][n][o] = sum_ck feats[b][ck][n] * PWh[o][ck], fp16 out, f32 in (transpose via LDS).
// grid (128 ntiles x 4 b), 256 thr, 4 waves (2x2): wave = 16n x 64o, BK=64, 16 k-steps.
// LDS: f32 A tile dbuf 2x[64ck][36f pad] + PW dbuf 2x16KB = 50KB.
#define FG1_LDS 51200
__global__ __launch_bounds__(256) void k_fg1(const float* __restrict__ feats,
                                             const _Float16* __restrict__ PWh,
                                             _Float16* __restrict__ f2d)
{
  extern __shared__ char smem[];                     // [0,18432): A f32 bufs; [18432,51200): PW bufs
  const int t = threadIdx.x, lane = t & 63, w = t >> 6;
  const int lo = lane & 15, hi = lane >> 4;
  const int n0 = blockIdx.x * 32, b = blockIdx.y;
  const int wr = w >> 1, wc = w & 1;
  const char* pwc = (const char*)PWh;

  float4 areg[2];
  auto loadA = [&](int s) {
    #pragma unroll
    for (int p = 0; p < 2; ++p) {
      int i = t + p * 256, row = i >> 3, slot = i & 7;   // row=ck 0..63, slot: 4 floats
      areg[p] = *(const float4*)(feats + ((size_t)(b * 1024 + s * 64 + row)) * 4096 + n0 + slot * 4);
    }
  };
  auto writeA = [&](int buf) {
    char* base = smem + buf * 9216;
    #pragma unroll
    for (int p = 0; p < 2; ++p) {
      int i = t + p * 256, row = i >> 3, slot = i & 7;
      *(float4*)(base + row * 144 + slot * 16) = areg[p]; // 36-float pad rows (144B, 16B-aligned)
    }
  };
  auto gllB = [&](int s, int buf) {
    char* base = smem + 18432 + buf * 16384;
    #pragma unroll
    for (int q = 0; q < 4; ++q) {
      int o = (w * 4 + q) * 8 + (lane >> 3);
      int slot = lane & 7;
      gll16(pwc + (size_t)o * 2048 + s * 128 + ((slot * 16) ^ ((o & 7) << 4)),
            base + (w * 4 + q) * 1024);
    }
  };

  const f32x4 zero4 = {0.f, 0.f, 0.f, 0.f};
  f32x4 acc[4];
  #pragma unroll
  for (int j2 = 0; j2 < 4; ++j2) acc[j2] = zero4;

  loadA(0); writeA(0); gllB(0, 0);
  for (int s = 0; s < 16; ++s) {
    __syncthreads();
    if (s < 15) { loadA(s + 1); gllB(s + 1, (s + 1) & 1); }
    const char* fb = smem + (s & 1) * 9216;
    const char* pb_ = smem + 18432 + (s & 1) * 16384;
    #pragma unroll
    for (int kk = 0; kk < 2; ++kk) {
      // A fragment: 8 f32 column reads + pack to fp16
      const int nl = wr * 16 + lo;
      float f0 = *(const float*)(fb + (kk * 32 + hi * 8 + 0) * 144 + nl * 4);
      float f1 = *(const float*)(fb + (kk * 32 + hi * 8 + 1) * 144 + nl * 4);
      float f2 = *(const float*)(fb + (kk * 32 + hi * 8 + 2) * 144 + nl * 4);
      float f3 = *(const float*)(fb + (kk * 32 + hi * 8 + 3) * 144 + nl * 4);
      float f4 = *(const float*)(fb + (kk * 32 + hi * 8 + 4) * 144 + nl * 4);
      float f5 = *(const float*)(fb + (kk * 32 + hi * 8 + 5) * 144 + nl * 4);
      float f6 = *(const float*)(fb + (kk * 32 + hi * 8 + 6) * 144 + nl * 4);
      float f7 = *(const float*)(fb + (kk * 32 + hi * 8 + 7) * 144 + nl * 4);
      u32x4 ua = { __builtin_bit_cast(uint32_t, __builtin_amdgcn_cvt_pkrtz(f0, f1)),
                   __builtin_bit_cast(uint32_t, __builtin_amdgcn_cvt_pkrtz(f2, f3)),
                   __builtin_bit_cast(uint32_t, __builtin_amdgcn_cvt_pkrtz(f4, f5)),
                   __builtin_bit_cast(uint32_t, __builtin_amdgcn_cvt_pkrtz(f6, f7)) };
      h8 af = __builtin_bit_cast(h8, ua);
      h8 bf[4];
      #pragma unroll
      for (int j2 = 0; j2 < 4; ++j2) {
        int o = wc * 64 + j2 * 16 + lo;
        bf[j2] = *(const h8*)(pb_ + o * 128 + ((kk * 64 + hi * 16) ^ ((o & 7) << 4)));
      }
      #pragma unroll
      for (int j2 = 0; j2 < 4; ++j2)
        acc[j2] = __builtin_amdgcn_mfma_f32_16x16x32_f16(af, bf[j2], acc[j2], 0, 0, 0);
    }
    if (s < 15) writeA((s + 1) & 1);
  }

  #pragma unroll
  for (int j2 = 0; j2 < 4; ++j2) {
    int o = wc * 64 + j2 * 16 + lo;
    #pragma unroll
    for (int r = 0; r < 4; ++r) {
      int n = n0 + wr * 16 + hi * 4 + r;
      f2d[((size_t)(b * 4096 + n)) * 128 + o] = (_Float16)acc[j2][r];
    }
  }
}

// ---------------- kernel 2: GEMM2  qk/v = F2D . Wh + bc; v-group (bx==2) to vt via LDS bounce ----------------
__global__ void k_gemm2(const _Float16* __restrict__ f2d, const _Float16* __restrict__ Wh,
                        const float* __restrict__ bc, _Float16* __restrict__ qkvt,
                        _Float16* __restrict__ vt)
{
  extern __shared__ char smem[];                     // A 32K + B 32K; bx==2 reuses for vtile
  const int t = threadIdx.x, lane = t & 63, w = t >> 6;
  const int lo = lane & 15, hi = lane >> 4;
  const int bx = blockIdx.x, n0 = blockIdx.y * 128, b = blockIdx.z;
  const int wr = w >> 1, wc = w & 1;
  const int nb = wr * 64, ob = wc * 64;
  const char* f2c = (const char*)f2d;

  #pragma unroll
  for (int q = 0; q < 8; ++q) {
    int c = w * 8 + q;
    int row = c * 4 + (lane >> 4);
    int col = ((lane & 15) * 16) ^ ((row & 7) << 4);
    gll16(f2c + ((size_t)(b * 4096 + n0 + row)) * 256 + col, smem + c * 1024);
    gll16((const char*)Wh + (size_t)(bx * 128 + row) * 256 + col, smem + 32768 + c * 1024);
  }
  __syncthreads();

  const f32x4 zero4 = {0.f, 0.f, 0.f, 0.f};
  f32x4 acc[4][4];
  #pragma unroll
  for (int i2 = 0; i2 < 4; ++i2)
    #pragma unroll
    for (int j2 = 0; j2 < 4; ++j2) acc[i2][j2] = zero4;

  #pragma unroll
  for (int kk = 0; kk < 4; ++kk) {
    const int cb = kk * 64 + hi * 16;
    h8 af[4], bf[4];
    #pragma unroll
    for (int i2 = 0; i2 < 4; ++i2) {
      int row = nb + i2 * 16 + lo;
      af[i2] = *(const h8*)(smem + row * 256 + (cb ^ ((row & 7) << 4)));
    }
    #pragma unroll
    for (int j2 = 0; j2 < 4; ++j2) {
      int row = ob + j2 * 16 + lo;
      bf[j2] = *(const h8*)(smem + 32768 + row * 256 + (cb ^ ((row & 7) << 4)));
    }
    #pragma unroll
    for (int i2 = 0; i2 < 4; ++i2)
      #pragma unroll
      for (int j2 = 0; j2 < 4; ++j2)
        acc[i2][j2] = __builtin_amdgcn_mfma_f32_16x16x32_f16(af[i2], bf[j2], acc[i2][j2], 0, 0, 0);
  }

  if (bx < 2) {
    #pragma unroll
    for (int j2 = 0; j2 < 4; ++j2) {
      int o = bx * 128 + ob + j2 * 16 + lo;
      float bias = bc[o];
      #pragma unroll
      for (int i2 = 0; i2 < 4; ++i2)
        #pragma unroll
        for (int r = 0; r < 4; ++r) {
          int n = n0 + nb + i2 * 16 + hi * 4 + r;
          qkvt[((size_t)(b * 4096 + n)) * 256 + o] = (_Float16)(acc[i2][j2][r] + bias);
        }
    }
  } else {
    // v-group: bounce through LDS (272B stride) and store transposed to vt[b][d][m]
    __syncthreads();
    #pragma unroll
    for (int j2 = 0; j2 < 4; ++j2) {
      int o = ob + j2 * 16 + lo;
      float bias = bc[256 + o];
      #pragma unroll
      for (int i2 = 0; i2 < 4; ++i2) {
        int nl = nb + i2 * 16 + hi * 4;
        h4 v4;
        #pragma unroll
        for (int r = 0; r < 4; ++r) v4[r] = (_Float16)(acc[i2][j2][r] + bias);
        *(h4*)(smem + o * 272 + nl * 2) = v4;
      }
    }
    __syncthreads();
    #pragma unroll
    for (int p2 = 0; p2 < 8; ++p2) {
      int i = t + p2 * 256, d = i >> 4, ch = i & 15;
      uint4 v = *(const uint4*)(smem + d * 272 + ch * 16);
      *(uint4*)((char*)vt + ((size_t)(b * 128 + d)) * 8192 + (n0 + ch * 8) * 2) = v;
    }
  }
}

// ---------------- kernel 3: split-KV(x8) flash attention, KVBLK=64 ----------------
// grid 1024 = 8p x 4b x 32qt; 128 q/block, 8 waves x 16 q; 8 iters x 64 keys.
// dbuf gll staging (64KB), swapped QK^T, log2 softmax, per-lane defer-max (+__any),
// shfl P-exchange. launch_bounds (512,4): VGPR cap 128 (R6 lesson: (512,8) cap 64 spilled).
#define ATT_LDS 65536
__global__ __launch_bounds__(512, 4) void k_attn_part(const _Float16* __restrict__ qkvt,
                                                      const _Float16* __restrict__ vt,
                                                      _Float16* __restrict__ opart,
                                                      float* __restrict__ mlm,
                                                      float* __restrict__ mll)
{
  extern __shared__ char smem[];                     // buf*32K: K[64][256B]; +16K: V[128][128B]
  const int t = threadIdx.x, lane = t & 63, w = t >> 6;  // w 0..7
  const int lo = lane & 15, hi = lane >> 4;
  const int id = blockIdx.x;
  const int vid = (id & 7) * 128 + (id >> 3);        // XCD x gets bp in {4x..4x+3}
  const int qt = vid & 31, bp = vid >> 5;
  const int b = bp >> 3, p = bp & 7;
  const int n0 = qt * 128;
  const char* qbase = (const char*)qkvt + (size_t)b * 4096 * 512;
  const char* vbase = (const char*)vt + (size_t)b * 128 * 8192;

  // Q B-fragments from global (one-time; log2e folded upstream)
  h8 bq[4];
  {
    const char* qr = qbase + (size_t)(n0 + w * 16 + lo) * 512;
    #pragma unroll
    for (int dk = 0; dk < 4; ++dk) bq[dk] = *(const h8*)(qr + dk * 64 + hi * 16);
  }

  // staging offsets: 2 K-gll + 2 V-gll per thread per tile (pre-swizzled source, linear dest)
  int koff[2], voff[2], dst_[2];
  #pragma unroll
  for (int q = 0; q < 2; ++q) {
    int c = w * 2 + q;                               // 0..15
    int krow = c * 4 + (lane >> 4);                  // 0..63
    koff[q] = krow * 512 + 256 + (((lane & 15) * 16) ^ ((krow & 7) << 4));
    int d = c * 8 + (lane >> 3);                     // 0..127
    voff[q] = d * 8192 + (((lane & 7) * 16) ^ ((d & 7) << 4));
    dst_[q] = c * 1024;
  }

  auto stage = [&](int m0, int buf) {
    char* kb = smem + buf * 32768;
    char* vb = kb + 16384;
    #pragma unroll
    for (int q = 0; q < 2; ++q) {
      gll16(qbase + (size_t)m0 * 512 + koff[q], kb + dst_[q]);
      gll16(vbase + (size_t)m0 * 2 + voff[q], vb + dst_[q]);
    }
  };

  const f32x4 zero4 = {0.f, 0.f, 0.f, 0.f};
  float m_run = -1e30f, l_run = 0.f;                 // per-lane partial l (own 16 keys/iter)
  f32x4 oacc[8];
  #pragma unroll
  for (int dt = 0; dt < 8; ++dt) oacc[dt] = zero4;

  const int slA = (hi & 1) * 32 + lo, slB = slA + 16;
  const bool up = (hi & 2) != 0;

  stage(p * 512, 0);
  __syncthreads();

  for (int it = 0; it < 8; ++it) {
    const int buf = it & 1;
    if (it < 7) stage(p * 512 + (it + 1) * 64, buf ^ 1);

    const char* kb = smem + buf * 32768;
    const char* vb = kb + 16384;

    // ---- S^T = K Q (log2 domain), 64 keys ----
    f32x4 s[4];
    #pragma unroll
    for (int mt = 0; mt < 4; ++mt) s[mt] = zero4;
    __builtin_amdgcn_s_setprio(1);
    #pragma unroll
    for (int mt = 0; mt < 4; ++mt) {
      #pragma unroll
      for (int dk = 0; dk < 4; ++dk) {
        int row = mt * 16 + lo;
        h8 ak = *(const h8*)(kb + row * 256 + ((dk * 64 + hi * 16) ^ ((row & 7) << 4)));
        s[mt] = __builtin_amdgcn_mfma_f32_16x16x32_f16(ak, bq[dk], s[mt], 0, 0, 0);
      }
    }
    __builtin_amdgcn_s_setprio(0);

    // ---- defer-max: per-lane test, cross-lane reduce only if any lane trips ----
    float mxl = fmaxf(fmaxf(fmaxf(s[0][0], s[0][1]), fmaxf(s[0][2], s[0][3])),
                      fmaxf(fmaxf(s[1][0], s[1][1]), fmaxf(s[1][2], s[1][3])));
    mxl = fmaxf(mxl, fmaxf(fmaxf(fmaxf(s[2][0], s[2][1]), fmaxf(s[2][2], s[2][3])),
                           fmaxf(fmaxf(s[3][0], s[3][1]), fmaxf(s[3][2], s[3][3]))));
    if (__any(mxl > m_run + 8.f)) {                  // wave-uniform branch (vcc), no DS op
      float mq = fmaxf(mxl, __shfl_xor(mxl, 16));
      mq = fmaxf(mq, __shfl_xor(mq, 32));
      float mnew = fmaxf(m_run, mq);
      float scn = EXP2(m_run - mnew);
      m_run = mnew;
      l_run *= scn;
      #pragma unroll
      for (int dt = 0; dt < 8; ++dt) oacc[dt] *= scn;
    }

    uint32_t pk[4][2];
    float rs = 0.f;
    #pragma unroll
    for (int mt = 0; mt < 4; ++mt) {
      float p0 = EXP2(s[mt][0] - m_run), p1 = EXP2(s[mt][1] - m_run);
      float p2 = EXP2(s[mt][2] - m_run), p3 = EXP2(s[mt][3] - m_run);
      rs += (p0 + p1) + (p2 + p3);
      pk[mt][0] = __builtin_bit_cast(uint32_t, __builtin_amdgcn_cvt_pkrtz(p0, p1));
      pk[mt][1] = __builtin_bit_cast(uint32_t, __builtin_amdgcn_cvt_pkrtz(p2, p3));
    }
    l_run += rs;

    // ---- PV in two 32-key halves: build P^T frag (shfl) + 8 MFMA each ----
    #pragma unroll
    for (int kk2 = 0; kk2 < 2; ++kk2) {
      uint32_t w0a = __shfl(pk[kk2 * 2][0], slA), w0b = __shfl(pk[kk2 * 2 + 1][0], slA);
      uint32_t w1a = __shfl(pk[kk2 * 2][1], slA), w1b = __shfl(pk[kk2 * 2 + 1][1], slA);
      uint32_t w2a = __shfl(pk[kk2 * 2][0], slB), w2b = __shfl(pk[kk2 * 2 + 1][0], slB);
      uint32_t w3a = __shfl(pk[kk2 * 2][1], slB), w3b = __shfl(pk[kk2 * 2 + 1][1], slB);
      u32x4 bw = { up ? w0b : w0a, up ? w1b : w1a, up ? w2b : w2a, up ? w3b : w3a };
      h8 bpf = __builtin_bit_cast(h8, bw);
      __builtin_amdgcn_s_setprio(1);
      #pragma unroll
      for (int dt = 0; dt < 8; ++dt) {
        int d = dt * 16 + lo;
        h8 av = *(const h8*)(vb + d * 128 + (((kk2 * 4 + hi) * 16) ^ ((d & 7) << 4)));
        oacc[dt] = __builtin_amdgcn_mfma_f32_16x16x32_f16(av, bpf, oacc[dt], 0, 0, 0);
      }
      __builtin_amdgcn_s_setprio(0);
    }

    if (it < 7) __syncthreads();
  }

  // ---- finalize: reduce l across hi-groups, store normalized fp16 partial + (m,l) ----
  l_run += __shfl_xor(l_run, 16);
  l_run += __shfl_xor(l_run, 32);
  float invl = 1.0f / l_run;
  _Float16* oph = opart + ((size_t)(p * 4 + b) * 128) * 4096;
  const int ncol = n0 + w * 16 + lo;
  #pragma unroll
  for (int dt = 0; dt < 8; ++dt)
    #pragma unroll
    for (int r = 0; r < 4; ++r) {
      int d = dt * 16 + hi * 4 + r;
      oph[(size_t)d * 4096 + ncol] = (_Float16)(oacc[dt][r] * invl);
    }
  if (hi == 0) {
    size_t mlbase = (size_t)(p * 4 + b) * 4096 + ncol;
    mlm[mlbase] = m_run;
    mll[mlbase] = l_run;
  }
}

// ---------------- kernel 4: combine 8 normalized KV-partials ----------------
__global__ void k_reduce(const _Float16* __restrict__ opart, const float* __restrict__ mlm,
                         const float* __restrict__ mll, float* __restrict__ out)
{
  int idx = blockIdx.x * 256 + threadIdx.x;          // 4b*128d*1024(n/4)
  int n4 = idx & 1023, d = (idx >> 10) & 127, b = idx >> 17;
  int n0 = n4 * 4;
  f32x4 m[8], lv[8];
  #pragma unroll
  for (int p = 0; p < 8; ++p) {
    size_t mb = (size_t)(p * 4 + b) * 4096 + n0;
    m[p]  = *(const f32x4*)(mlm + mb);
    lv[p] = *(const f32x4*)(mll + mb);
  }
  f32x4 M = m[0];
  #pragma unroll
  for (int p = 1; p < 8; ++p)
    #pragma unroll
    for (int j = 0; j < 4; ++j) M[j] = fmaxf(M[j], m[p][j]);
  f32x4 denom = {0.f, 0.f, 0.f, 0.f}, num = {0.f, 0.f, 0.f, 0.f};
  #pragma unroll
  for (int p = 0; p < 8; ++p) {
    h4 o = *(const h4*)(opart + ((size_t)((p * 4 + b) * 128 + d)) * 4096 + n0);
    #pragma unroll
    for (int j = 0; j < 4; ++j) {
      float wgt = lv[p][j] * EXP2(m[p][j] - M[j]);
      denom[j] += wgt;
      num[j]   += (float)o[j] * wgt;
    }
  }
  f32x4 r;
  #pragma unroll
  for (int j = 0; j < 4; ++j) r[j] = num[j] / denom[j];
  *(f32x4*)(out + ((size_t)(b * 128 + d)) * 4096 + n0) = r;
}

extern "C" void kernel_launch(void* const* d_in, const int* in_sizes, int n_in,
                              void* d_out, int out_size, void* d_ws, size_t ws_size,
                              hipStream_t stream)
{
  const float* feats = (const float*)d_in[0];
  const float* pw = (const float*)d_in[1];
  const float* pb = (const float*)d_in[2];
  const float* w1 = (const float*)d_in[3];
  const float* b1 = (const float*)d_in[4];
  const float* w2 = (const float*)d_in[5];
  const float* b2 = (const float*)d_in[6];
  const float* w3 = (const float*)d_in[7];
  const float* b3 = (const float*)d_in[8];
  char* ws = (char*)d_ws;
  _Float16* PWh = (_Float16*)(ws + WS_PWH);
  _Float16* Wh = (_Float16*)(ws + WS_WH);
  float* bc = (float*)(ws + WS_BC);
  _Float16* f2d = (_Float16*)(ws + WS_F2D);
  _Float16* qkvt = (_Float16*)(ws + WS_QKVT);
  _Float16* vt = (_Float16*)(ws + WS_VT);
  _Float16* opart = (_Float16*)(ws + WS_OP);
  float* mlm = (float*)(ws + WS_MLM);
  float* mll = (float*)(ws + WS_MLL);
  float* out = (float*)d_out;

  hipLaunchKernelGGL(k_cvt, dim3(704), dim3(256), 0, stream,
                     pw, pb, w1, b1, w2, b2, w3, b3, PWh, Wh, bc);
  hipLaunchKernelGGL(k_fg1, dim3(128, 4), dim3(256), FG1_LDS, stream, feats, PWh, f2d);
  hipLaunchKernelGGL(k_gemm2, dim3(3, 32, 4), dim3(256), 65536, stream, f2d, Wh, bc, qkvt, vt);
  hipLaunchKernelGGL(k_attn_part, dim3(1024), dim3(512), ATT_LDS, stream, qkvt, vt, opart, mlm, mll);
  hipLaunchKernelGGL(k_reduce, dim3(2048), dim3(256), 0, stream, opart, mlm, mll, out);
}